// Round 1
// baseline (415.444 us; speedup 1.0000x reference)
//
#include <hip/hip_runtime.h>
#include <math.h>

// Problem shape (fixed by reference setup_inputs):
//   images [32][256][64][64] fp32, words [32][32][768] fp32, mask [32][32] bool,
//   W [256][768] fp32, b [256] fp32
//   out0 weighted_words [32][256][64][64], out1 attn_out [32][32][64][64], fp32 concat.
#define B_   32
#define NC_  256
#define HW_  4096
#define MW_  32
#define E_   768
#define NEG_BIG -3.0e38f

// Workspace layout (float offsets). Total ~10.2 MB.
#define PART_OFF 0          // partial GEMM: 8 chunks * 32b * 32m * 256c = 2097152 floats
#define WP_OFF   2097152    // words_p [b][c][m]: 262144 floats
#define WT_OFF   2359296    // W transposed [e][c]: 196608 floats
#define MASK_OFF 2555904    // normalized mask: 1024 ints

// ---------------------------------------------------------------------------
// Prep: tiled transpose of W (256x768 -> 768x256) + mask normalization.
// Mask may arrive as int32, raw bool bytes, or float; detect from first 1KB.
// ---------------------------------------------------------------------------
__global__ __launch_bounds__(256) void prep_kernel(
    const float* __restrict__ W, const void* __restrict__ mask_raw,
    float* __restrict__ WT, int* __restrict__ maskn) {
  const int tid = threadIdx.x;
  if (blockIdx.x < 192) {
    // 32x32 tile transpose; tiles: 8 (c) x 24 (e)
    __shared__ float t[32][33];
    const int tc = blockIdx.x / 24, te = blockIdx.x % 24;
    const int c0 = tc * 32, e0 = te * 32;
    const int tx = tid & 31, ty = tid >> 5;
#pragma unroll
    for (int k = 0; k < 4; ++k) {
      const int r = ty + 8 * k;
      t[r][tx] = W[(c0 + r) * E_ + e0 + tx];  // coalesced over tx
    }
    __syncthreads();
#pragma unroll
    for (int k = 0; k < 4; ++k) {
      const int r = ty + 8 * k;
      WT[(e0 + r) * NC_ + c0 + tx] = t[tx][r];  // coalesced over tx
    }
  } else {
    // Mask layout detection + normalize to int[1024].
    __shared__ int is_word;  // 1 if 4-byte-per-element layout (int32 or fp32)
    if (tid == 0) is_word = 1;
    __syncthreads();
    const int* mi = (const int*)mask_raw;
    const int v = mi[tid];  // reads only first 1024 bytes: safe for any layout
    if (v != 0 && v != 1 && v != 0x3F800000) is_word = 0;
    __syncthreads();
    if (is_word) {
#pragma unroll
      for (int j = 0; j < 4; ++j) { const int i = j * 256 + tid; maskn[i] = (mi[i] != 0); }
    } else {
      const unsigned char* mb = (const unsigned char*)mask_raw;
#pragma unroll
      for (int j = 0; j < 4; ++j) { const int i = j * 256 + tid; maskn[i] = (mb[i] != 0); }
    }
  }
}

// ---------------------------------------------------------------------------
// Stage 1a: words_p partials. Block = (batch, e-chunk of 96). lane = c.
// WT[e][c] coalesced vector load; words[b][m][e] wave-uniform -> s_load.
// part layout [chunk][b][m][c] so stores are coalesced over lanes.
// ---------------------------------------------------------------------------
__global__ __launch_bounds__(256) void stage1_partial(
    const float* __restrict__ words, const float* __restrict__ WT,
    float* __restrict__ part) {
  const int c = threadIdx.x;
  const int b = blockIdx.x >> 3;
  const int chunk = blockIdx.x & 7;
  const int e0 = chunk * 96;
  const float* wrow = words + (size_t)b * MW_ * E_;
  float acc[32];
#pragma unroll
  for (int m = 0; m < 32; ++m) acc[m] = 0.f;
  for (int e = e0; e < e0 + 96; e += 2) {
    const float w0 = WT[(size_t)e * NC_ + c];
    const float w1 = WT[(size_t)(e + 1) * NC_ + c];
#pragma unroll
    for (int m = 0; m < 32; ++m) {
      acc[m] = fmaf(w0, wrow[m * E_ + e], acc[m]);       // uniform 2nd operand
      acc[m] = fmaf(w1, wrow[m * E_ + e + 1], acc[m]);
    }
  }
  float* pp = part + ((size_t)chunk * 32 + b) * 32 * 256;
#pragma unroll
  for (int m = 0; m < 32; ++m) pp[m * 256 + c] = acc[m];  // coalesced
}

// ---------------------------------------------------------------------------
// Stage 1b: reduce 8 partials + bias -> wp[b][c][m] (m contiguous for stage 2).
// ---------------------------------------------------------------------------
__global__ __launch_bounds__(256) void stage1_reduce(
    const float* __restrict__ part, const float* __restrict__ bias,
    float* __restrict__ wp) {
  const int idx = blockIdx.x * 256 + threadIdx.x;  // (b, m, c), c innermost
  const int c = idx & 255;
  const int m = (idx >> 8) & 31;
  const int b = idx >> 13;
  float s = bias[c];
#pragma unroll
  for (int k = 0; k < 8; ++k)
    s += part[(((size_t)k * 32 + b) * 32 + m) * 256 + c];  // coalesced
  wp[((size_t)b * 256 + c) * 32 + m] = s;
}

// ---------------------------------------------------------------------------
// Stage 2: per-pixel attention. lane = pixel (perfect coalescing on images &
// outputs); wp[b][c][m] and mask are wave-uniform -> SGPR scalar loads.
// Grid: 32 batches x 16 tiles of 256 pixels.
// ---------------------------------------------------------------------------
__global__ __launch_bounds__(256) void attention_main(
    const float* __restrict__ images, const float* __restrict__ wp,
    const int* __restrict__ maskn, float* __restrict__ out_w,
    float* __restrict__ out_a) {
  const int b = blockIdx.x >> 4;
  const int p = ((blockIdx.x & 15) << 8) + threadIdx.x;
  const float* img = images + (size_t)b * NC_ * HW_ + p;
  const float* wpb = wp + (size_t)b * NC_ * MW_;

  // scores: s[m] = sum_c img[c,p] * wp[c,m]
  float s[32];
#pragma unroll
  for (int m = 0; m < 32; ++m) s[m] = 0.f;
#pragma unroll 2
  for (int c = 0; c < 256; ++c) {
    const float iv = img[(size_t)c << 12];           // coalesced over lanes
#pragma unroll
    for (int m = 0; m < 32; ++m)
      s[m] = fmaf(iv, wpb[(c << 5) + m], s[m]);      // uniform -> SGPR operand
  }

  // mask bits (wave-uniform)
  unsigned mbits = 0;
#pragma unroll
  for (int m = 0; m < 32; ++m)
    mbits |= (maskn[(b << 5) + m] != 0 ? 1u : 0u) << m;

  // softmax over m (scale 1/sqrt(256) = 0.0625); masked -> exactly 0
  float mx = NEG_BIG;
#pragma unroll
  for (int m = 0; m < 32; ++m) {
    s[m] *= 0.0625f;
    if (!((mbits >> m) & 1u)) mx = fmaxf(mx, s[m]);
  }
  float sum = 0.f;
#pragma unroll
  for (int m = 0; m < 32; ++m) {
    const float ev = ((mbits >> m) & 1u) ? 0.f : __expf(s[m] - mx);
    s[m] = ev;
    sum += ev;
  }
  const float inv = 1.f / sum;
#pragma unroll
  for (int m = 0; m < 32; ++m) {
    const float a = s[m] * inv;
    s[m] = a;
    out_a[((size_t)(b * 32 + m) << 12) + p] = a;     // coalesced
  }

  // weighted words: out[c,p] = sum_m wp[c,m] * a[m]
#pragma unroll 2
  for (int c = 0; c < 256; ++c) {
    float o = 0.f;
#pragma unroll
    for (int m = 0; m < 32; ++m)
      o = fmaf(wpb[(c << 5) + m], s[m], o);          // uniform -> SGPR operand
    out_w[((size_t)(b * 256 + c) << 12) + p] = o;    // coalesced
  }
}

// ---------------------------------------------------------------------------
extern "C" void kernel_launch(void* const* d_in, const int* in_sizes, int n_in,
                              void* d_out, int out_size, void* d_ws, size_t ws_size,
                              hipStream_t stream) {
  const float* images = (const float*)d_in[0];
  const float* words  = (const float*)d_in[1];
  const void*  mask   = d_in[2];
  const float* W      = (const float*)d_in[3];
  const float* bias   = (const float*)d_in[4];

  float* ws   = (float*)d_ws;
  float* part = ws + PART_OFF;
  float* wp   = ws + WP_OFF;
  float* WT   = ws + WT_OFF;
  int*   maskn = (int*)(ws + MASK_OFF);

  float* out_w = (float*)d_out;
  float* out_a = out_w + (size_t)B_ * NC_ * HW_;

  prep_kernel<<<193, 256, 0, stream>>>(W, mask, WT, maskn);
  stage1_partial<<<256, 256, 0, stream>>>(words, WT, part);
  stage1_reduce<<<1024, 256, 0, stream>>>(part, bias, wp);
  attention_main<<<512, 256, 0, stream>>>(images, wp, maskn, out_w, out_a);
}

// Round 2
// 335.998 us; speedup vs baseline: 1.2364x; 1.2364x over previous
//
#include <hip/hip_runtime.h>
#include <math.h>

// Problem shape (fixed by reference setup_inputs):
//   images [32][256][64][64] fp32, words [32][32][768] fp32, mask [32][32] bool,
//   W [256][768] fp32, b [256] fp32
//   out0 weighted_words [32][256][64][64], out1 attn_out [32][32][64][64], fp32 concat.
#define B_   32
#define NC_  256
#define HW_  4096
#define MW_  32
#define E_   768
#define NEG_BIG -3.0e38f

// Workspace layout (float offsets). Total ~13.4 MB.
#define PART_OFF   0          // partial GEMM: 8 chunks * 32b * 32m * 256c = 2097152 floats
#define WP_OFF     2097152    // words_p [b][c][m]: 262144 floats
#define WT_OFF     2359296    // W transposed [e][c]: 196608 floats
#define WORDST_OFF 2555904    // words transposed [b][e][m]: 786432 floats
#define MASK_OFF   3342336    // normalized mask: 1024 ints

// ---------------------------------------------------------------------------
// Prep: tiled transposes (W 256x768 -> WT 768x256; words[b] 32x768 ->
// wordsT[b] 768x32) + mask normalization.
// Blocks 0..191: W transpose. 192..959: words transpose. 960: mask.
// ---------------------------------------------------------------------------
__global__ __launch_bounds__(256) void prep_kernel(
    const float* __restrict__ W, const float* __restrict__ words,
    const void* __restrict__ mask_raw,
    float* __restrict__ WT, float* __restrict__ wordsT,
    int* __restrict__ maskn) {
  const int tid = threadIdx.x;
  const int tx = tid & 31, ty = tid >> 5;
  if (blockIdx.x < 192) {
    // W: 32x32 tile transpose; tiles: 8 (c) x 24 (e)
    __shared__ float t[32][33];
    const int tc = blockIdx.x / 24, te = blockIdx.x % 24;
    const int c0 = tc * 32, e0 = te * 32;
#pragma unroll
    for (int k = 0; k < 4; ++k) {
      const int r = ty + 8 * k;
      t[r][tx] = W[(c0 + r) * E_ + e0 + tx];  // coalesced over tx
    }
    __syncthreads();
#pragma unroll
    for (int k = 0; k < 4; ++k) {
      const int r = ty + 8 * k;
      WT[(e0 + r) * NC_ + c0 + tx] = t[tx][r];  // coalesced over tx
    }
  } else if (blockIdx.x < 960) {
    // words[b]: 32(m) x 768(e) -> wordsT[b]: 768(e) x 32(m). tiles: 32 b x 24 e
    __shared__ float t[32][33];
    const int idx = blockIdx.x - 192;
    const int b = idx / 24, te = idx % 24;
    const int e0 = te * 32;
    const float* wsrc = words + (size_t)b * MW_ * E_;
    float* wdst = wordsT + (size_t)b * E_ * MW_;
#pragma unroll
    for (int k = 0; k < 4; ++k) {
      const int m = ty + 8 * k;
      t[m][tx] = wsrc[m * E_ + e0 + tx];        // coalesced over tx (e)
    }
    __syncthreads();
#pragma unroll
    for (int k = 0; k < 4; ++k) {
      const int e = ty + 8 * k;
      wdst[(e0 + e) * MW_ + tx] = t[tx][e];     // coalesced over tx (m)
    }
  } else {
    // Mask layout detection + normalize to int[1024].
    __shared__ int is_word;  // 1 if 4-byte-per-element layout (int32 or fp32)
    if (tid == 0) is_word = 1;
    __syncthreads();
    const int* mi = (const int*)mask_raw;
    const int v = mi[tid];  // reads only first 1024 bytes: safe for any layout
    if (v != 0 && v != 1 && v != 0x3F800000) is_word = 0;
    __syncthreads();
    if (is_word) {
#pragma unroll
      for (int j = 0; j < 4; ++j) { const int i = j * 256 + tid; maskn[i] = (mi[i] != 0); }
    } else {
      const unsigned char* mb = (const unsigned char*)mask_raw;
#pragma unroll
      for (int j = 0; j < 4; ++j) { const int i = j * 256 + tid; maskn[i] = (mb[i] != 0); }
    }
  }
}

// ---------------------------------------------------------------------------
// Stage 1a: words_p partials. Block = (batch, e-chunk of 96). lane = c.
// WT[e][c] coalesced vector load; wordsT[b][e][0..31] is wave-uniform AND
// contiguous -> 2x s_load_dwordx16 per e (this was 32 strided s_loads in R1).
// ---------------------------------------------------------------------------
__global__ __launch_bounds__(256) void stage1_partial(
    const float* __restrict__ wordsT, const float* __restrict__ WT,
    float* __restrict__ part) {
  const int c = threadIdx.x;
  const int b = blockIdx.x >> 3;
  const int chunk = blockIdx.x & 7;
  const int e0 = chunk * 96;
  const float* wt = wordsT + (size_t)b * E_ * MW_;
  float acc[32];
#pragma unroll
  for (int m = 0; m < 32; ++m) acc[m] = 0.f;
#pragma unroll 2
  for (int e = e0; e < e0 + 96; ++e) {
    const float wv = WT[(size_t)e * NC_ + c];   // coalesced over lanes
    const float* wr = wt + e * MW_;             // uniform, contiguous
#pragma unroll
    for (int m = 0; m < 32; ++m) acc[m] = fmaf(wv, wr[m], acc[m]);
  }
  float* pp = part + ((size_t)chunk * 32 + b) * 32 * 256;
#pragma unroll
  for (int m = 0; m < 32; ++m) pp[m * 256 + c] = acc[m];  // coalesced
}

// ---------------------------------------------------------------------------
// Stage 1b: reduce 8 partials + bias -> wp[b][c][m] (m contiguous for stage 2).
// ---------------------------------------------------------------------------
__global__ __launch_bounds__(256) void stage1_reduce(
    const float* __restrict__ part, const float* __restrict__ bias,
    float* __restrict__ wp) {
  const int idx = blockIdx.x * 256 + threadIdx.x;  // (b, m, c), c innermost
  const int c = idx & 255;
  const int m = (idx >> 8) & 31;
  const int b = idx >> 13;
  float s = bias[c];
#pragma unroll
  for (int k = 0; k < 8; ++k)
    s += part[(((size_t)k * 32 + b) * 32 + m) * 256 + c];  // coalesced
  wp[((size_t)b * 256 + c) * 32 + m] = s;
}

// ---------------------------------------------------------------------------
// Stage 2: per-pixel attention. lane = pixel (perfect coalescing on images &
// outputs); wp[b][c][m] and mask are wave-uniform -> SGPR scalar loads.
// 16-deep load batching + 1-iteration prefetch: 16 nontemporal loads in
// flight while 512 FMAs (1024 cyc) retire the previous batch -> hides the
// ~900-cyc HBM miss latency that capped R1 at 1.3 TB/s.
// Grid: 32 batches x 16 tiles of 256 pixels.
// ---------------------------------------------------------------------------
__global__ __launch_bounds__(256) void attention_main(
    const float* __restrict__ images, const float* __restrict__ wp,
    const int* __restrict__ maskn, float* __restrict__ out_w,
    float* __restrict__ out_a) {
  const int b = blockIdx.x >> 4;
  const int p = ((blockIdx.x & 15) << 8) + threadIdx.x;
  const float* img = images + (size_t)b * NC_ * HW_ + p;
  const float* wpb = wp + (size_t)b * NC_ * MW_;

  // scores: s[m] = sum_c img[c,p] * wp[c,m]
  float s[32];
#pragma unroll
  for (int m = 0; m < 32; ++m) s[m] = 0.f;

  float cur[16];
#pragma unroll
  for (int j = 0; j < 16; ++j)
    cur[j] = __builtin_nontemporal_load(img + ((size_t)j << 12));

#pragma unroll 1
  for (int c0 = 0; c0 < 256; c0 += 16) {
    float nxt[16];
    if (c0 + 16 < 256) {
#pragma unroll
      for (int j = 0; j < 16; ++j)
        nxt[j] = __builtin_nontemporal_load(img + ((size_t)(c0 + 16 + j) << 12));
    }
#pragma unroll
    for (int j = 0; j < 16; ++j) {
#pragma unroll
      for (int m = 0; m < 32; ++m)
        s[m] = fmaf(cur[j], wpb[((c0 + j) << 5) + m], s[m]);  // SGPR operand
    }
#pragma unroll
    for (int j = 0; j < 16; ++j) cur[j] = nxt[j];  // dead on last iter
  }

  // mask bits (wave-uniform)
  unsigned mbits = 0;
#pragma unroll
  for (int m = 0; m < 32; ++m)
    mbits |= (maskn[(b << 5) + m] != 0 ? 1u : 0u) << m;

  // softmax over m (scale 1/sqrt(256) = 0.0625); masked -> exactly 0
  float mx = NEG_BIG;
#pragma unroll
  for (int m = 0; m < 32; ++m) {
    s[m] *= 0.0625f;
    if (!((mbits >> m) & 1u)) mx = fmaxf(mx, s[m]);
  }
  float sum = 0.f;
#pragma unroll
  for (int m = 0; m < 32; ++m) {
    const float ev = ((mbits >> m) & 1u) ? 0.f : __expf(s[m] - mx);
    s[m] = ev;
    sum += ev;
  }
  const float inv = 1.f / sum;
#pragma unroll
  for (int m = 0; m < 32; ++m) {
    const float a = s[m] * inv;
    s[m] = a;
    __builtin_nontemporal_store(a, out_a + ((size_t)(b * 32 + m) << 12) + p);
  }

  // weighted words: out[c,p] = sum_m wp[c,m] * a[m]
#pragma unroll 1
  for (int c0 = 0; c0 < 256; c0 += 8) {
#pragma unroll
    for (int jc = 0; jc < 8; ++jc) {
      const int c = c0 + jc;
      float o = 0.f;
#pragma unroll
      for (int m = 0; m < 32; ++m)
        o = fmaf(wpb[(c << 5) + m], s[m], o);  // SGPR operand
      __builtin_nontemporal_store(o, out_w + ((size_t)(b * 256 + c) << 12) + p);
    }
  }
}

// ---------------------------------------------------------------------------
extern "C" void kernel_launch(void* const* d_in, const int* in_sizes, int n_in,
                              void* d_out, int out_size, void* d_ws, size_t ws_size,
                              hipStream_t stream) {
  const float* images = (const float*)d_in[0];
  const float* words  = (const float*)d_in[1];
  const void*  mask   = d_in[2];
  const float* W      = (const float*)d_in[3];
  const float* bias   = (const float*)d_in[4];

  float* ws     = (float*)d_ws;
  float* part   = ws + PART_OFF;
  float* wp     = ws + WP_OFF;
  float* WT     = ws + WT_OFF;
  float* wordsT = ws + WORDST_OFF;
  int*   maskn  = (int*)(ws + MASK_OFF);

  float* out_w = (float*)d_out;
  float* out_a = out_w + (size_t)B_ * NC_ * HW_;

  prep_kernel<<<961, 256, 0, stream>>>(W, words, mask, WT, wordsT, maskn);
  stage1_partial<<<256, 256, 0, stream>>>(wordsT, WT, part);
  stage1_reduce<<<1024, 256, 0, stream>>>(part, bias, wp);
  attention_main<<<512, 256, 0, stream>>>(images, wp, maskn, out_w, out_a);
}